// Round 8
// baseline (407.484 us; speedup 1.0000x reference)
//
#include <hip/hip_runtime.h>
#include <math.h>
#include <string.h>

#define W 1024
#define H 1024
#define HW (1024*1024)
#define NP 24                 // B*C planes

typedef float  f32x4  __attribute__((ext_vector_type(4)));
typedef short  bf16x8 __attribute__((ext_vector_type(8)));

struct Weights { float w[273]; };   // w80[161]@0, w40[81]@161, w15[31]@242

#define P1PIT 328             // pass-1 LDS pitch (shorts), ≡8 mod 64

// planesT blocked layout: elem(sp, y, x) at sp*HW + (y>>5)*32768 + x*32 + (y&31)
// -> pass-1 writes one contiguous 8KB region per block per sigma;
// -> pass-2 A-frag (8 consecutive y at fixed x) = one 16B-aligned global load.

// ---------- helpers ----------

__device__ __forceinline__ unsigned fenc(float f) {
  unsigned u = __float_as_uint(f);
  return (u & 0x80000000u) ? ~u : (u | 0x80000000u);
}
__device__ __forceinline__ float fdec(unsigned e) {
  unsigned u = (e & 0x80000000u) ? (e & 0x7fffffffu) : ~e;
  return __uint_as_float(u);
}
__device__ __forceinline__ unsigned bfbits(float f) {   // f32 -> bf16 bits, RNE
  unsigned u = __float_as_uint(f);
  return (u + 0x7fffu + ((u >> 16) & 1u)) >> 16;
}

__device__ __forceinline__ void minmax_reduce4(float lmn, float lmx, unsigned* mm, float* red) {
  #pragma unroll
  for (int off = 32; off > 0; off >>= 1) {
    lmn = fminf(lmn, __shfl_xor(lmn, off));
    lmx = fmaxf(lmx, __shfl_xor(lmx, off));
  }
  const int tid = threadIdx.x;
  const int wid = tid >> 6;
  if ((tid & 63) == 0) { red[wid] = lmn; red[4 + wid] = lmx; }
  __syncthreads();
  if (tid == 0) {
    float mn = fminf(fminf(red[0], red[1]), fminf(red[2], red[3]));
    float mx = fmaxf(fmaxf(red[4], red[5]), fmaxf(red[6], red[7]));
    atomicMin(mm, fenc(mn));
    atomicMax(mm + 1, fenc(mx));
  }
}

// ---------- init: Toeplitz B-fragment table [3][6][64 lanes] x 8 bf16 ----------

__global__ void msr_fraginit(Weights wt, ushort* __restrict__ frag, unsigned* __restrict__ mm) {
  const int tid = threadIdx.x;
  if (tid == 0) { mm[0] = 0xFFFFFFFFu; mm[1] = 0u; }
  const int pads[3] = {80, 40, 15};
  const int woff[3] = {0, 161, 242};
  const int t0s[3]  = {11, 13, 15};
  for (int e = tid; e < 3 * 6 * 64; e += 256) {
    const int s = e / 384;
    const int rem = e - s * 384;
    const int k = rem >> 6;
    const int lane = rem & 63;
    const int pad = pads[s];
    const int d = pad + (t0s[s] + 2 * k) * 16 - 256;
    ushort* dst = frag + e * 8;
    for (int j = 0; j < 8; ++j) {
      const int kk = ((lane >> 4) << 3) + j;
      const int c  = lane & 15;
      const int idx = d + kk - c;
      float v = (idx >= 0 && idx <= 2 * pad) ? wt.w[woff[s] + idx] : 0.f;
      dst[j] = (ushort)bfbits(v);
    }
  }
}

// ---------- pass 1: horizontal blur (3 sigmas) -> blocked transposed bf16 planes ----------
// Block (128 thr, 2 waves): out tile 32 rows(y, = one 32-strip) x 128 cols(x).

template<int NK, int C0, int FB>
__device__ __forceinline__ void h_round(const short* __restrict__ lds,
                                        const bf16x8* __restrict__ fragv,
                                        ushort* __restrict__ pT,   // + sp*HW + strip*32768
                                        int lane, int rowshort, int x16, int yin) {
  bf16x8 fr[NK];
  #pragma unroll
  for (int k = 0; k < NK; ++k) fr[k] = fragv[(FB + k) * 64 + lane];
  #pragma unroll
  for (int tx = 0; tx < 8; ++tx) {
    f32x4 acc = {0.f, 0.f, 0.f, 0.f};
    #pragma unroll
    for (int k = 0; k < NK; ++k) {
      bf16x8 a = *(const bf16x8*)(lds + rowshort + tx * 16 + C0 + 32 * k);
      acc = __builtin_amdgcn_mfma_f32_16x16x32_bf16(a, fr[k], acc, 0, 0, 0);
    }
    const unsigned lo = bfbits(acc[0]) | (bfbits(acc[1]) << 16);
    const unsigned hi = bfbits(acc[2]) | (bfbits(acc[3]) << 16);
    *(uint2*)(pT + (size_t)(x16 + tx * 16) * 32 + yin) = make_uint2(lo, hi);
  }
}

__global__ __launch_bounds__(128, 3) void msr_hblur3(
    const float* __restrict__ img, ushort* __restrict__ planesT,
    const bf16x8* __restrict__ fragv) {
  __shared__ __align__(16) short lds[32 * P1PIT];   // 20992 B
  const int tid = threadIdx.x;
  const int orig = blockIdx.x + (blockIdx.y << 3) + (blockIdx.z << 8);
  const int l = (orig & 7) * 768 + (orig >> 3);     // bijective XCD swizzle
  const int bx = l & 7;            // x-tile (128 wide, halo axis)
  const int by = (l >> 3) & 31;    // y-strip (32 tall)
  const int bp = l >> 8;           // plane
  const int x0 = bx * 128, y0 = by * 32;
  const float* sp = img + (size_t)bp * HW;
  const int row = tid >> 2, c4 = tid & 3;
  const bool interior = (bx >= 1 && bx <= 6);
  #pragma unroll
  for (int it = 0; it < 20; ++it) {
    const int ccpx = 4 * c4 + 16 * it;
    const int gx0 = x0 - 96 + ccpx;
    unsigned lo, hi;
    if (interior || (gx0 >= 0 && gx0 + 4 <= W)) {
      const float4 v = *(const float4*)(sp + (size_t)(y0 + row) * W + gx0);
      lo = bfbits(v.x) | (bfbits(v.y) << 16);
      hi = bfbits(v.z) | (bfbits(v.w) << 16);
    } else {
      unsigned us[4];
      #pragma unroll
      for (int j = 0; j < 4; ++j) {
        int gx = gx0 + j;
        gx = gx < 0 ? -gx : (gx >= W ? 2 * W - 2 - gx : gx);
        us[j] = bfbits(sp[(size_t)(y0 + row) * W + gx]);
      }
      lo = us[0] | (us[1] << 16); hi = us[2] | (us[3] << 16);
    }
    *(uint2*)(lds + row * P1PIT + ccpx) = make_uint2(lo, hi);
  }
  __syncthreads();

  const int lane = tid & 63;
  const int wrow = (tid >> 6) * 16;
  const int q = lane >> 4;
  const int rowshort = (wrow + (lane & 15)) * P1PIT + q * 8;
  const int x16 = x0 + (lane & 15);
  const int yin = wrow + q * 4;                    // within-strip y
  const size_t sb = (size_t)by * 32768;

  h_round<6, 16, 0>(lds, fragv, planesT + (size_t)(0 * NP + bp) * HW + sb, lane, rowshort, x16, yin);
  h_round<4, 48, 6>(lds, fragv, planesT + (size_t)(1 * NP + bp) * HW + sb, lane, rowshort, x16, yin);
  h_round<2, 80, 12>(lds, fragv, planesT + (size_t)(2 * NP + bp) * HW + sb, lane, rowshort, x16, yin);
}

// ---------- pass 2: vertical blur, A-frags DIRECT from global (no LDS staging) ----------
// Frag y = ybase - PE + tx*16 + 32k, ybase = y0 + q*8: always ≡0 mod 8 -> one 16B load
// from the blocked planesT layout. L2/L3 serve the 5x Toeplitz reuse; no barriers.

template<int NK, int PE, int FB>
__device__ __forceinline__ void p2g_round(const ushort* __restrict__ pTs,
                                          const bf16x8* __restrict__ fragv,
                                          int xa, int ybase, int lane, bool interior,
                                          float* accL) {
  bf16x8 fr[NK];
  #pragma unroll
  for (int k = 0; k < NK; ++k) fr[k] = fragv[(FB + k) * 64 + lane];
  const size_t xoff = (size_t)xa << 5;
  #pragma unroll
  for (int tx = 0; tx < 8; ++tx) {
    f32x4 acc = {0.f, 0.f, 0.f, 0.f};
    #pragma unroll
    for (int k = 0; k < NK; ++k) {
      const int y = ybase - PE + tx * 16 + 32 * k;
      bf16x8 a;
      if (interior || (unsigned)y <= (unsigned)(H - 8)) {
        a = *(const bf16x8*)(pTs + (((size_t)(unsigned)(y >> 5)) << 15) + xoff + (y & 31));
      } else {
        union { ushort u[8]; bf16x8 v; } t;
        #pragma unroll
        for (int j = 0; j < 8; ++j) {
          int g = y + j;
          g = g < 0 ? -g : (g >= H ? 2 * H - 2 - g : g);
          t.u[j] = pTs[(((size_t)(g >> 5)) << 15) + xoff + (g & 31)];
        }
        a = t.v;
      }
      acc = __builtin_amdgcn_mfma_f32_16x16x32_bf16(a, fr[k], acc, 0, 0, 0);
    }
    #pragma unroll
    for (int r = 0; r < 4; ++r) accL[tx * 4 + r] -= __logf(acc[r] + 2e-6f);
  }
}

__global__ __launch_bounds__(256) __attribute__((amdgpu_waves_per_eu(4, 5)))
void msr_vblur3(
    const ushort* __restrict__ planesT, const float* __restrict__ img,
    float* __restrict__ out, const bf16x8* __restrict__ fragv, unsigned* __restrict__ mm) {
  __shared__ float red[8];
  const int tid = threadIdx.x;
  const int orig = blockIdx.x + (blockIdx.y << 4) + (blockIdx.z << 7);
  const int l = (orig & 7) * 384 + (orig >> 3);     // bijective (3072 = 8*384)
  const int byt = l & 7;           // y-tile (128 tall, halo axis -> same XCD)
  const int bxt = (l >> 3) & 15;   // x-tile (64 wide)
  const int bp = l >> 7;
  const int x0 = bxt * 64, y0 = byt * 128;
  const int lane = tid & 63;
  const int wrow = (tid >> 6) * 16;
  const int q = lane >> 4;
  const int c = lane & 15;
  const int xa = x0 + wrow + c;          // A-frag x (16 rows per wave)
  const int ybase = y0 + q * 8;          // frag y = ybase - PE + tx*16 + 32k
  const int xb = x0 + wrow + 4 * q;      // C store: 4 consecutive x per lane
  const int ycb = y0 + c;                // C store y (+ tx*16)
  const bool interior = (byt >= 1 && byt <= 6);

  const ushort* pT0 = planesT + (size_t)(0 * NP + bp) * HW;
  const ushort* pT1 = planesT + (size_t)(1 * NP + bp) * HW;
  const ushort* pT2 = planesT + (size_t)(2 * NP + bp) * HW;

  // accL init from img
  float accL[32];
  const float* ip = img + (size_t)bp * HW;
  #pragma unroll
  for (int tx = 0; tx < 8; ++tx) {
    const float4 v = *(const float4*)(ip + (size_t)(ycb + tx * 16) * W + xb);
    accL[tx * 4 + 0] = 3.f * __logf(v.x + 1e-6f);
    accL[tx * 4 + 1] = 3.f * __logf(v.y + 1e-6f);
    accL[tx * 4 + 2] = 3.f * __logf(v.z + 1e-6f);
    accL[tx * 4 + 3] = 3.f * __logf(v.w + 1e-6f);
  }

  p2g_round<6, 80, 0>(pT0, fragv, xa, ybase, lane, interior, accL);
  p2g_round<4, 48, 6>(pT1, fragv, xa, ybase, lane, interior, accL);
  p2g_round<2, 16, 12>(pT2, fragv, xa, ybase, lane, interior, accL);

  float* op = out + (size_t)bp * HW;
  float lmn = 3.4e38f, lmx = -3.4e38f;
  #pragma unroll
  for (int tx = 0; tx < 8; ++tx) {
    #pragma unroll
    for (int r = 0; r < 4; ++r) {
      lmn = fminf(lmn, accL[tx * 4 + r]);
      lmx = fmaxf(lmx, accL[tx * 4 + r]);
    }
    *(float4*)(op + (size_t)(ycb + tx * 16) * W + xb) =
        make_float4(accL[tx * 4 + 0], accL[tx * 4 + 1], accL[tx * 4 + 2], accL[tx * 4 + 3]);
  }
  minmax_reduce4(lmn, lmx, mm, red);
}

// ---------- normalize ----------

__global__ __launch_bounds__(256) void msr_norm(float* __restrict__ out,
                                                const unsigned* __restrict__ mm) {
  const size_t i = ((size_t)blockIdx.x * 256 + threadIdx.x) * 4;
  const float mn = fdec(mm[0]);
  const float mx = fdec(mm[1]);
  const float sc = 255.f / (mx - mn);
  float4 v = *(float4*)(out + i);
  v.x = (v.x - mn) * sc;
  v.y = (v.y - mn) * sc;
  v.z = (v.z - mn) * sc;
  v.w = (v.w - mn) * sc;
  *(float4*)(out + i) = v;
}

// ---------- host-side weights (mirrors reference float math) ----------

static void compute_weights(Weights* wt) {
  memset(wt, 0, sizeof(Weights));
  const int   ntap[3]  = {161, 81, 31};
  const int   off[3]   = {0, 161, 242};
  const float sigma[3] = {80.f, 40.f, 15.f};
  for (int s = 0; s < 3; ++s) {
    const int k = ntap[s];
    float g[161];
    float sum = 0.f;
    for (int i = 0; i < k; ++i) {
      float x = (float)i - (float)(k - 1) * 0.5f;
      g[i] = expf(-(x * x) / (2.f * sigma[s] * sigma[s]));
      sum += g[i];
    }
    const float inv = 1.f / sum;
    for (int i = 0; i < k; ++i) wt->w[off[s] + i] = g[i] * inv;
  }
}

// ---------- launch ----------

extern "C" void kernel_launch(void* const* d_in, const int* in_sizes, int n_in,
                              void* d_out, int out_size, void* d_ws, size_t ws_size,
                              hipStream_t stream) {
  const float* img = (const float*)d_in[0];
  float* out = (float*)d_out;
  unsigned* mm = (unsigned*)d_ws;
  ushort* frag = (ushort*)((char*)d_ws + 256);
  ushort* planesT = (ushort*)((char*)d_ws + 32768);

  Weights wt;
  compute_weights(&wt);

  msr_fraginit<<<1, 256, 0, stream>>>(wt, frag, mm);
  msr_hblur3<<<dim3(8, 32, NP), 128, 0, stream>>>(img, planesT, (const bf16x8*)frag);
  msr_vblur3<<<dim3(16, 8, NP), 256, 0, stream>>>(planesT, img, out, (const bf16x8*)frag, mm);
  msr_norm<<<(unsigned)((size_t)NP * HW / 1024), 256, 0, stream>>>(out, mm);
}

// Round 9
// 360.489 us; speedup vs baseline: 1.1304x; 1.1304x over previous
//
#include <hip/hip_runtime.h>
#include <math.h>
#include <string.h>

#define W 1024
#define H 1024
#define HW (1024*1024)
#define NP 24                 // B*C planes

typedef float  f32x4  __attribute__((ext_vector_type(4)));
typedef short  bf16x8 __attribute__((ext_vector_type(8)));

struct Weights { float w[273]; };   // w80[161]@0, w40[81]@161, w15[31]@242

#define P1PIT 328             // pass-1 LDS pitch (shorts), ≡8 mod 64

// planesT blocked layout: elem(sp, y, x) at sp*HW + (y>>5)*32768 + x*32 + (y&31)
// -> pass-1 writes one contiguous 8KB region per block per sigma;
// -> pass-2 A-frag (8 consecutive y at fixed x) = one 16B-aligned global load.

// ---------- helpers ----------

__device__ __forceinline__ unsigned fenc(float f) {
  unsigned u = __float_as_uint(f);
  return (u & 0x80000000u) ? ~u : (u | 0x80000000u);
}
__device__ __forceinline__ float fdec(unsigned e) {
  unsigned u = (e & 0x80000000u) ? (e & 0x7fffffffu) : ~e;
  return __uint_as_float(u);
}
__device__ __forceinline__ unsigned bfbits(float f) {   // f32 -> bf16 bits, RNE
  unsigned u = __float_as_uint(f);
  return (u + 0x7fffu + ((u >> 16) & 1u)) >> 16;
}

__device__ __forceinline__ void minmax_reduce4(float lmn, float lmx, unsigned* mm, float* red) {
  #pragma unroll
  for (int off = 32; off > 0; off >>= 1) {
    lmn = fminf(lmn, __shfl_xor(lmn, off));
    lmx = fmaxf(lmx, __shfl_xor(lmx, off));
  }
  const int tid = threadIdx.x;
  const int wid = tid >> 6;
  if ((tid & 63) == 0) { red[wid] = lmn; red[4 + wid] = lmx; }
  __syncthreads();
  if (tid == 0) {
    float mn = fminf(fminf(red[0], red[1]), fminf(red[2], red[3]));
    float mx = fmaxf(fmaxf(red[4], red[5]), fmaxf(red[6], red[7]));
    atomicMin(mm, fenc(mn));
    atomicMax(mm + 1, fenc(mx));
  }
}

// ---------- init: Toeplitz B-fragment table [3][6][64 lanes] x 8 bf16 ----------

__global__ void msr_fraginit(Weights wt, ushort* __restrict__ frag, unsigned* __restrict__ mm) {
  const int tid = threadIdx.x;
  if (tid == 0) { mm[0] = 0xFFFFFFFFu; mm[1] = 0u; }
  const int pads[3] = {80, 40, 15};
  const int woff[3] = {0, 161, 242};
  const int t0s[3]  = {11, 13, 15};
  for (int e = tid; e < 3 * 6 * 64; e += 256) {
    const int s = e / 384;
    const int rem = e - s * 384;
    const int k = rem >> 6;
    const int lane = rem & 63;
    const int pad = pads[s];
    const int d = pad + (t0s[s] + 2 * k) * 16 - 256;
    ushort* dst = frag + e * 8;
    for (int j = 0; j < 8; ++j) {
      const int kk = ((lane >> 4) << 3) + j;
      const int c  = lane & 15;
      const int idx = d + kk - c;
      float v = (idx >= 0 && idx <= 2 * pad) ? wt.w[woff[s] + idx] : 0.f;
      dst[j] = (ushort)bfbits(v);
    }
  }
}

// ---------- pass 1: horizontal blur (3 sigmas) -> blocked transposed bf16 planes ----------
// Block (128 thr, 2 waves): out tile 32 rows(y, = one 32-strip) x 128 cols(x).

template<int NK, int C0, int FB>
__device__ __forceinline__ void h_round(const short* __restrict__ lds,
                                        const bf16x8* __restrict__ fragv,
                                        ushort* __restrict__ pT,   // + sp*HW + strip*32768
                                        int lane, int rowshort, int x16, int yin) {
  bf16x8 fr[NK];
  #pragma unroll
  for (int k = 0; k < NK; ++k) fr[k] = fragv[(FB + k) * 64 + lane];
  #pragma unroll
  for (int tx = 0; tx < 8; ++tx) {
    f32x4 acc = {0.f, 0.f, 0.f, 0.f};
    #pragma unroll
    for (int k = 0; k < NK; ++k) {
      bf16x8 a = *(const bf16x8*)(lds + rowshort + tx * 16 + C0 + 32 * k);
      acc = __builtin_amdgcn_mfma_f32_16x16x32_bf16(a, fr[k], acc, 0, 0, 0);
    }
    const unsigned lo = bfbits(acc[0]) | (bfbits(acc[1]) << 16);
    const unsigned hi = bfbits(acc[2]) | (bfbits(acc[3]) << 16);
    *(uint2*)(pT + (size_t)(x16 + tx * 16) * 32 + yin) = make_uint2(lo, hi);
  }
}

__global__ __launch_bounds__(128, 3) void msr_hblur3(
    const float* __restrict__ img, ushort* __restrict__ planesT,
    const bf16x8* __restrict__ fragv) {
  __shared__ __align__(16) short lds[32 * P1PIT];   // 20992 B
  const int tid = threadIdx.x;
  const int orig = blockIdx.x + (blockIdx.y << 3) + (blockIdx.z << 8);
  const int l = (orig & 7) * 768 + (orig >> 3);     // bijective XCD swizzle
  const int bx = l & 7;            // x-tile (128 wide, halo axis)
  const int by = (l >> 3) & 31;    // y-strip (32 tall)
  const int bp = l >> 8;           // plane
  const int x0 = bx * 128, y0 = by * 32;
  const float* sp = img + (size_t)bp * HW;
  const int row = tid >> 2, c4 = tid & 3;
  const bool interior = (bx >= 1 && bx <= 6);
  #pragma unroll
  for (int it = 0; it < 20; ++it) {
    const int ccpx = 4 * c4 + 16 * it;
    const int gx0 = x0 - 96 + ccpx;
    unsigned lo, hi;
    if (interior || (gx0 >= 0 && gx0 + 4 <= W)) {
      const float4 v = *(const float4*)(sp + (size_t)(y0 + row) * W + gx0);
      lo = bfbits(v.x) | (bfbits(v.y) << 16);
      hi = bfbits(v.z) | (bfbits(v.w) << 16);
    } else {
      unsigned us[4];
      #pragma unroll
      for (int j = 0; j < 4; ++j) {
        int gx = gx0 + j;
        gx = gx < 0 ? -gx : (gx >= W ? 2 * W - 2 - gx : gx);
        us[j] = bfbits(sp[(size_t)(y0 + row) * W + gx]);
      }
      lo = us[0] | (us[1] << 16); hi = us[2] | (us[3] << 16);
    }
    *(uint2*)(lds + row * P1PIT + ccpx) = make_uint2(lo, hi);
  }
  __syncthreads();

  const int lane = tid & 63;
  const int wrow = (tid >> 6) * 16;
  const int q = lane >> 4;
  const int rowshort = (wrow + (lane & 15)) * P1PIT + q * 8;
  const int x16 = x0 + (lane & 15);
  const int yin = wrow + q * 4;                    // within-strip y
  const size_t sb = (size_t)by * 32768;

  h_round<6, 16, 0>(lds, fragv, planesT + (size_t)(0 * NP + bp) * HW + sb, lane, rowshort, x16, yin);
  h_round<4, 48, 6>(lds, fragv, planesT + (size_t)(1 * NP + bp) * HW + sb, lane, rowshort, x16, yin);
  h_round<2, 80, 12>(lds, fragv, planesT + (size_t)(2 * NP + bp) * HW + sb, lane, rowshort, x16, yin);
}

// ---------- pass 2: vertical blur, A-frags DIRECT from global (no LDS staging) ----------
// Frag y = ybase - PE + tx*16 + 32k, ybase = y0 + q*8: always ≡0 mod 8 -> one 16B load
// from the blocked planesT layout. L2/L3 serve the 5x Toeplitz reuse; no barriers.
// amdgpu_waves_per_eu(2,3): the empirically-validated envelope (round 7: 116 VGPR,
// zero spill, WRITE_SIZE exactly logical). Round 8's (4,5) shrank to 64 VGPR and
// spilled 170 MB of accL/frag traffic -> 2x regression. Do NOT narrow this again.

template<int NK, int PE, int FB>
__device__ __forceinline__ void p2g_round(const ushort* __restrict__ pTs,
                                          const bf16x8* __restrict__ fragv,
                                          int xa, int ybase, int lane, bool interior,
                                          float* accL) {
  bf16x8 fr[NK];
  #pragma unroll
  for (int k = 0; k < NK; ++k) fr[k] = fragv[(FB + k) * 64 + lane];
  const size_t xoff = (size_t)xa << 5;
  #pragma unroll
  for (int tx = 0; tx < 8; ++tx) {
    f32x4 acc = {0.f, 0.f, 0.f, 0.f};
    #pragma unroll
    for (int k = 0; k < NK; ++k) {
      const int y = ybase - PE + tx * 16 + 32 * k;
      bf16x8 a;
      if (interior || (unsigned)y <= (unsigned)(H - 8)) {
        a = *(const bf16x8*)(pTs + (((size_t)(unsigned)(y >> 5)) << 15) + xoff + (y & 31));
      } else {
        union { ushort u[8]; bf16x8 v; } t;
        #pragma unroll
        for (int j = 0; j < 8; ++j) {
          int g = y + j;
          g = g < 0 ? -g : (g >= H ? 2 * H - 2 - g : g);
          t.u[j] = pTs[(((size_t)(g >> 5)) << 15) + xoff + (g & 31)];
        }
        a = t.v;
      }
      acc = __builtin_amdgcn_mfma_f32_16x16x32_bf16(a, fr[k], acc, 0, 0, 0);
    }
    #pragma unroll
    for (int r = 0; r < 4; ++r) accL[tx * 4 + r] -= __logf(acc[r] + 2e-6f);
  }
}

__global__ __launch_bounds__(256) __attribute__((amdgpu_waves_per_eu(2, 3)))
void msr_vblur3(
    const ushort* __restrict__ planesT, const float* __restrict__ img,
    float* __restrict__ out, const bf16x8* __restrict__ fragv, unsigned* __restrict__ mm) {
  __shared__ float red[8];
  const int tid = threadIdx.x;
  const int orig = blockIdx.x + (blockIdx.y << 4) + (blockIdx.z << 7);
  const int l = (orig & 7) * 384 + (orig >> 3);     // bijective (3072 = 8*384)
  const int byt = l & 7;           // y-tile (128 tall, halo axis -> same XCD)
  const int bxt = (l >> 3) & 15;   // x-tile (64 wide)
  const int bp = l >> 7;
  const int x0 = bxt * 64, y0 = byt * 128;
  const int lane = tid & 63;
  const int wrow = (tid >> 6) * 16;
  const int q = lane >> 4;
  const int c = lane & 15;
  const int xa = x0 + wrow + c;          // A-frag x (16 rows per wave)
  const int ybase = y0 + q * 8;          // frag y = ybase - PE + tx*16 + 32k
  const int xb = x0 + wrow + 4 * q;      // C store: 4 consecutive x per lane
  const int ycb = y0 + c;                // C store y (+ tx*16)
  const bool interior = (byt >= 1 && byt <= 6);

  const ushort* pT0 = planesT + (size_t)(0 * NP + bp) * HW;
  const ushort* pT1 = planesT + (size_t)(1 * NP + bp) * HW;
  const ushort* pT2 = planesT + (size_t)(2 * NP + bp) * HW;

  // accL init from img
  float accL[32];
  const float* ip = img + (size_t)bp * HW;
  #pragma unroll
  for (int tx = 0; tx < 8; ++tx) {
    const float4 v = *(const float4*)(ip + (size_t)(ycb + tx * 16) * W + xb);
    accL[tx * 4 + 0] = 3.f * __logf(v.x + 1e-6f);
    accL[tx * 4 + 1] = 3.f * __logf(v.y + 1e-6f);
    accL[tx * 4 + 2] = 3.f * __logf(v.z + 1e-6f);
    accL[tx * 4 + 3] = 3.f * __logf(v.w + 1e-6f);
  }

  p2g_round<6, 80, 0>(pT0, fragv, xa, ybase, lane, interior, accL);
  p2g_round<4, 48, 6>(pT1, fragv, xa, ybase, lane, interior, accL);
  p2g_round<2, 16, 12>(pT2, fragv, xa, ybase, lane, interior, accL);

  float* op = out + (size_t)bp * HW;
  float lmn = 3.4e38f, lmx = -3.4e38f;
  #pragma unroll
  for (int tx = 0; tx < 8; ++tx) {
    #pragma unroll
    for (int r = 0; r < 4; ++r) {
      lmn = fminf(lmn, accL[tx * 4 + r]);
      lmx = fmaxf(lmx, accL[tx * 4 + r]);
    }
    *(float4*)(op + (size_t)(ycb + tx * 16) * W + xb) =
        make_float4(accL[tx * 4 + 0], accL[tx * 4 + 1], accL[tx * 4 + 2], accL[tx * 4 + 3]);
  }
  minmax_reduce4(lmn, lmx, mm, red);
}

// ---------- normalize ----------

__global__ __launch_bounds__(256) void msr_norm(float* __restrict__ out,
                                                const unsigned* __restrict__ mm) {
  const size_t i = ((size_t)blockIdx.x * 256 + threadIdx.x) * 4;
  const float mn = fdec(mm[0]);
  const float mx = fdec(mm[1]);
  const float sc = 255.f / (mx - mn);
  float4 v = *(float4*)(out + i);
  v.x = (v.x - mn) * sc;
  v.y = (v.y - mn) * sc;
  v.z = (v.z - mn) * sc;
  v.w = (v.w - mn) * sc;
  *(float4*)(out + i) = v;
}

// ---------- host-side weights (mirrors reference float math) ----------

static void compute_weights(Weights* wt) {
  memset(wt, 0, sizeof(Weights));
  const int   ntap[3]  = {161, 81, 31};
  const int   off[3]   = {0, 161, 242};
  const float sigma[3] = {80.f, 40.f, 15.f};
  for (int s = 0; s < 3; ++s) {
    const int k = ntap[s];
    float g[161];
    float sum = 0.f;
    for (int i = 0; i < k; ++i) {
      float x = (float)i - (float)(k - 1) * 0.5f;
      g[i] = expf(-(x * x) / (2.f * sigma[s] * sigma[s]));
      sum += g[i];
    }
    const float inv = 1.f / sum;
    for (int i = 0; i < k; ++i) wt->w[off[s] + i] = g[i] * inv;
  }
}

// ---------- launch ----------

extern "C" void kernel_launch(void* const* d_in, const int* in_sizes, int n_in,
                              void* d_out, int out_size, void* d_ws, size_t ws_size,
                              hipStream_t stream) {
  const float* img = (const float*)d_in[0];
  float* out = (float*)d_out;
  unsigned* mm = (unsigned*)d_ws;
  ushort* frag = (ushort*)((char*)d_ws + 256);
  ushort* planesT = (ushort*)((char*)d_ws + 32768);

  Weights wt;
  compute_weights(&wt);

  msr_fraginit<<<1, 256, 0, stream>>>(wt, frag, mm);
  msr_hblur3<<<dim3(8, 32, NP), 128, 0, stream>>>(img, planesT, (const bf16x8*)frag);
  msr_vblur3<<<dim3(16, 8, NP), 256, 0, stream>>>(planesT, img, out, (const bf16x8*)frag, mm);
  msr_norm<<<(unsigned)((size_t)NP * HW / 1024), 256, 0, stream>>>(out, mm);
}

// Round 10
// 263.380 us; speedup vs baseline: 1.5471x; 1.3687x over previous
//
#include <hip/hip_runtime.h>
#include <math.h>
#include <string.h>

#define W 1024
#define H 1024
#define HW (1024*1024)
#define NP 24                 // B*C planes

typedef float  f32x4  __attribute__((ext_vector_type(4)));
typedef short  bf16x8 __attribute__((ext_vector_type(8)));

struct Weights { float w[273]; };   // w80[161]@0, w40[81]@161, w15[31]@242

// LDS pitches (shorts), ≡8 mod 64. Staged widths = full MFMA read footprint:
// 24(q*8) + 7*16 + NK*32 + 8 = 304 / 240 / 176.
#define P1PIT 328
#define P2P80 328
#define P2P40 264
#define P2P15 200

#define NSLOT 64              // min/max atomic buckets (Guideline 12: 3072 blocks x 2
                              // same-address atomics serialized ~100us; 64-way spread)

// planesT blocked layout: elem(sp, y, x) at sp*HW + (y>>5)*32768 + x*32 + (y&31)

// ---------- helpers ----------

__device__ __forceinline__ unsigned fenc(float f) {
  unsigned u = __float_as_uint(f);
  return (u & 0x80000000u) ? ~u : (u | 0x80000000u);
}
__device__ __forceinline__ float fdec(unsigned e) {
  unsigned u = (e & 0x80000000u) ? (e & 0x7fffffffu) : ~e;
  return __uint_as_float(u);
}
__device__ __forceinline__ unsigned bfbits(float f) {   // f32 -> bf16 bits, RNE
  unsigned u = __float_as_uint(f);
  return (u + 0x7fffu + ((u >> 16) & 1u)) >> 16;
}

// block-reduce then ONE atomicMin+Max into a per-block bucket
__device__ __forceinline__ void minmax_reduce4(float lmn, float lmx, unsigned* mm,
                                               float* red, int slot) {
  #pragma unroll
  for (int off = 32; off > 0; off >>= 1) {
    lmn = fminf(lmn, __shfl_xor(lmn, off));
    lmx = fmaxf(lmx, __shfl_xor(lmx, off));
  }
  const int tid = threadIdx.x;
  const int wid = tid >> 6;
  if ((tid & 63) == 0) { red[wid] = lmn; red[4 + wid] = lmx; }
  __syncthreads();
  if (tid == 0) {
    float mn = fminf(fminf(red[0], red[1]), fminf(red[2], red[3]));
    float mx = fmaxf(fmaxf(red[4], red[5]), fmaxf(red[6], red[7]));
    atomicMin(mm + 2 * slot, fenc(mn));
    atomicMax(mm + 2 * slot + 1, fenc(mx));
  }
}

// ---------- init: Toeplitz B-fragment table [3][6][64 lanes] x 8 bf16 ----------

__global__ void msr_fraginit(Weights wt, ushort* __restrict__ frag, unsigned* __restrict__ mm) {
  const int tid = threadIdx.x;
  if (tid < NSLOT) { mm[2 * tid] = 0xFFFFFFFFu; mm[2 * tid + 1] = 0u; }
  const int pads[3] = {80, 40, 15};
  const int woff[3] = {0, 161, 242};
  const int t0s[3]  = {11, 13, 15};
  for (int e = tid; e < 3 * 6 * 64; e += 256) {
    const int s = e / 384;
    const int rem = e - s * 384;
    const int k = rem >> 6;
    const int lane = rem & 63;
    const int pad = pads[s];
    const int d = pad + (t0s[s] + 2 * k) * 16 - 256;
    ushort* dst = frag + e * 8;
    for (int j = 0; j < 8; ++j) {
      const int kk = ((lane >> 4) << 3) + j;
      const int c  = lane & 15;
      const int idx = d + kk - c;
      float v = (idx >= 0 && idx <= 2 * pad) ? wt.w[woff[s] + idx] : 0.f;
      dst[j] = (ushort)bfbits(v);
    }
  }
}

// ---------- slot reducer: 64 bucket-pairs -> mm[128], mm[129] ----------

__global__ void msr_mmred(unsigned* __restrict__ mm) {
  const int tid = threadIdx.x;   // 64 threads, 1 wave
  unsigned e = mm[2 * tid];      // encoded min
  unsigned f = mm[2 * tid + 1];  // encoded max
  #pragma unroll
  for (int off = 32; off > 0; off >>= 1) {
    unsigned eo = (unsigned)__shfl_xor((int)e, off);
    unsigned fo = (unsigned)__shfl_xor((int)f, off);
    e = eo < e ? eo : e;
    f = fo > f ? fo : f;
  }
  if (tid == 0) { mm[2 * NSLOT] = e; mm[2 * NSLOT + 1] = f; }
}

// ---------- pass 1: horizontal blur (3 sigmas) -> blocked transposed bf16 planes ----------
// Block (128 thr, 2 waves): out tile 32 rows(y, = one 32-strip) x 128 cols(x).

template<int NK, int C0, int FB>
__device__ __forceinline__ void h_round(const short* __restrict__ lds,
                                        const bf16x8* __restrict__ fragv,
                                        ushort* __restrict__ pT,   // + sp*HW + strip*32768
                                        int lane, int rowshort, int x16, int yin) {
  bf16x8 fr[NK];
  #pragma unroll
  for (int k = 0; k < NK; ++k) fr[k] = fragv[(FB + k) * 64 + lane];
  #pragma unroll
  for (int tx = 0; tx < 8; ++tx) {
    f32x4 acc = {0.f, 0.f, 0.f, 0.f};
    #pragma unroll
    for (int k = 0; k < NK; ++k) {
      bf16x8 a = *(const bf16x8*)(lds + rowshort + tx * 16 + C0 + 32 * k);
      acc = __builtin_amdgcn_mfma_f32_16x16x32_bf16(a, fr[k], acc, 0, 0, 0);
    }
    const unsigned lo = bfbits(acc[0]) | (bfbits(acc[1]) << 16);
    const unsigned hi = bfbits(acc[2]) | (bfbits(acc[3]) << 16);
    *(uint2*)(pT + (size_t)(x16 + tx * 16) * 32 + yin) = make_uint2(lo, hi);
  }
}

__global__ __launch_bounds__(128, 3) void msr_hblur3(
    const float* __restrict__ img, ushort* __restrict__ planesT,
    const bf16x8* __restrict__ fragv) {
  __shared__ __align__(16) short lds[32 * P1PIT];   // 20992 B
  const int tid = threadIdx.x;
  const int orig = blockIdx.x + (blockIdx.y << 3) + (blockIdx.z << 8);
  const int l = (orig & 7) * 768 + (orig >> 3);     // bijective XCD swizzle
  const int bx = l & 7;            // x-tile (128 wide, halo axis)
  const int by = (l >> 3) & 31;    // y-strip (32 tall)
  const int bp = l >> 8;           // plane
  const int x0 = bx * 128, y0 = by * 32;
  const float* sp = img + (size_t)bp * HW;
  const int row = tid >> 2, c4 = tid & 3;
  const bool interior = (bx >= 1 && bx <= 6);
  #pragma unroll
  for (int it = 0; it < 20; ++it) {
    const int ccpx = 4 * c4 + 16 * it;
    const int gx0 = x0 - 96 + ccpx;
    unsigned lo, hi;
    if (interior || (gx0 >= 0 && gx0 + 4 <= W)) {
      const float4 v = *(const float4*)(sp + (size_t)(y0 + row) * W + gx0);
      lo = bfbits(v.x) | (bfbits(v.y) << 16);
      hi = bfbits(v.z) | (bfbits(v.w) << 16);
    } else {
      unsigned us[4];
      #pragma unroll
      for (int j = 0; j < 4; ++j) {
        int gx = gx0 + j;
        gx = gx < 0 ? -gx : (gx >= W ? 2 * W - 2 - gx : gx);
        us[j] = bfbits(sp[(size_t)(y0 + row) * W + gx]);
      }
      lo = us[0] | (us[1] << 16); hi = us[2] | (us[3] << 16);
    }
    *(uint2*)(lds + row * P1PIT + ccpx) = make_uint2(lo, hi);
  }
  __syncthreads();

  const int lane = tid & 63;
  const int wrow = (tid >> 6) * 16;
  const int q = lane >> 4;
  const int rowshort = (wrow + (lane & 15)) * P1PIT + q * 8;
  const int x16 = x0 + (lane & 15);
  const int yin = wrow + q * 4;                    // within-strip y
  const size_t sb = (size_t)by * 32768;

  h_round<6, 16, 0>(lds, fragv, planesT + (size_t)(0 * NP + bp) * HW + sb, lane, rowshort, x16, yin);
  h_round<4, 48, 6>(lds, fragv, planesT + (size_t)(1 * NP + bp) * HW + sb, lane, rowshort, x16, yin);
  h_round<2, 80, 12>(lds, fragv, planesT + (size_t)(2 * NP + bp) * HW + sb, lane, rowshort, x16, yin);
}

// ---------- pass 2: round-7 structure (LDS staging + reg prefetch one round ahead) ----------
// waves_per_eu(2,3): validated envelope (116 VGPR, zero spill). (4,5) spilled — don't.

template<int NCH, int WD>
__device__ __forceinline__ void p2_prefetch(const ushort* __restrict__ pTs, int xrow,
                                            int ystart, int c4, uint4 (&pre)[10]) {
  #pragma unroll
  for (int i = 0; i < NCH; ++i) {
    const int ccpx = 8 * c4 + 32 * i;
    if (ccpx < WD) {
      const int gy = ystart + ccpx;                // multiple of 8 -> never straddles a strip
      if (gy >= 0 && gy + 8 <= H) {
        pre[i] = *(const uint4*)(pTs + (size_t)(gy >> 5) * 32768 + (size_t)xrow * 32 + (gy & 31));
      } else {
        union { ushort u[8]; uint4 v; } t;
        #pragma unroll
        for (int j = 0; j < 8; ++j) {
          int g = gy + j;
          g = g < 0 ? -g : (g >= H ? 2 * H - 2 - g : g);
          t.u[j] = pTs[(size_t)(g >> 5) * 32768 + (size_t)xrow * 32 + (g & 31)];
        }
        pre[i] = t.v;
      }
    }
  }
}

template<int NCH, int WD, int PIT>
__device__ __forceinline__ void p2_wlds(short* __restrict__ lds, int row, int c4,
                                        const uint4 (&pre)[10]) {
  #pragma unroll
  for (int i = 0; i < NCH; ++i) {
    const int ccpx = 8 * c4 + 32 * i;
    if (ccpx < WD) *(uint4*)(lds + row * PIT + ccpx) = pre[i];
  }
}

template<int NK, int PIT, int FB>
__device__ __forceinline__ void p2_convlog(const short* __restrict__ lds,
                                           const bf16x8* __restrict__ fragv,
                                           int lane, int wrow, float* accL) {
  const int rowshort = (wrow + (lane & 15)) * PIT + (lane >> 4) * 8;
  bf16x8 fr[NK];
  #pragma unroll
  for (int k = 0; k < NK; ++k) fr[k] = fragv[(FB + k) * 64 + lane];
  #pragma unroll
  for (int tx = 0; tx < 8; ++tx) {
    f32x4 acc = {0.f, 0.f, 0.f, 0.f};
    #pragma unroll
    for (int k = 0; k < NK; ++k) {
      bf16x8 a = *(const bf16x8*)(lds + rowshort + tx * 16 + 32 * k);
      acc = __builtin_amdgcn_mfma_f32_16x16x32_bf16(a, fr[k], acc, 0, 0, 0);
    }
    #pragma unroll
    for (int r = 0; r < 4; ++r) accL[tx * 4 + r] -= __logf(acc[r] + 2e-6f);
  }
}

__global__ __launch_bounds__(256) __attribute__((amdgpu_waves_per_eu(2, 3)))
void msr_vblur3(
    const ushort* __restrict__ planesT, const float* __restrict__ img,
    float* __restrict__ out, const bf16x8* __restrict__ fragv, unsigned* __restrict__ mm) {
  __shared__ __align__(16) short lds[64 * P2P80];   // 41984 B -> 3 blocks/CU
  __shared__ float red[8];
  const int tid = threadIdx.x;
  const int orig = blockIdx.x + (blockIdx.y << 4) + (blockIdx.z << 7);
  const int l = (orig & 7) * 384 + (orig >> 3);     // bijective (3072 = 8*384)
  const int byt = l & 7;           // y-tile (128 tall, halo axis -> same XCD)
  const int bxt = (l >> 3) & 15;   // x-tile (64 wide)
  const int bp = l >> 7;
  const int x0 = bxt * 64, y0 = byt * 128;
  const int row = tid >> 2, c4 = tid & 3;           // row in [0,64)
  const int lane = tid & 63;
  const int wrow = (tid >> 6) * 16;
  const int q = lane >> 4;
  const int xb = x0 + wrow + 4 * q;       // C rows = x (4 consecutive per lane)
  const int ycb = y0 + (lane & 15);       // C cols = y (+ tx*16)

  const ushort* pT0 = planesT + (size_t)(0 * NP + bp) * HW;
  const ushort* pT1 = planesT + (size_t)(1 * NP + bp) * HW;
  const ushort* pT2 = planesT + (size_t)(2 * NP + bp) * HW;

  uint4 pre[10];
  p2_prefetch<10, 304>(pT0, x0 + row, y0 - 80, c4, pre);   // sigma80 window in flight

  // accL init from img (long VALU stretch hides the prefetch latency)
  float accL[32];
  const float* ip = img + (size_t)bp * HW;
  #pragma unroll
  for (int tx = 0; tx < 8; ++tx) {
    const float4 v = *(const float4*)(ip + (size_t)(ycb + tx * 16) * W + xb);
    accL[tx * 4 + 0] = 3.f * __logf(v.x + 1e-6f);
    accL[tx * 4 + 1] = 3.f * __logf(v.y + 1e-6f);
    accL[tx * 4 + 2] = 3.f * __logf(v.z + 1e-6f);
    accL[tx * 4 + 3] = 3.f * __logf(v.w + 1e-6f);
  }

  // round sigma80
  p2_wlds<10, 304, P2P80>(lds, row, c4, pre);
  __syncthreads();
  p2_prefetch<8, 240>(pT1, x0 + row, y0 - 48, c4, pre);    // next round in flight
  p2_convlog<6, P2P80, 0>(lds, fragv, lane, wrow, accL);
  __syncthreads();
  // round sigma40
  p2_wlds<8, 240, P2P40>(lds, row, c4, pre);
  __syncthreads();
  p2_prefetch<6, 176>(pT2, x0 + row, y0 - 16, c4, pre);
  p2_convlog<4, P2P40, 6>(lds, fragv, lane, wrow, accL);
  __syncthreads();
  // round sigma15
  p2_wlds<6, 176, P2P15>(lds, row, c4, pre);
  __syncthreads();
  p2_convlog<2, P2P15, 12>(lds, fragv, lane, wrow, accL);

  float* op = out + (size_t)bp * HW;
  float lmn = 3.4e38f, lmx = -3.4e38f;
  #pragma unroll
  for (int tx = 0; tx < 8; ++tx) {
    #pragma unroll
    for (int r = 0; r < 4; ++r) {
      lmn = fminf(lmn, accL[tx * 4 + r]);
      lmx = fmaxf(lmx, accL[tx * 4 + r]);
    }
    *(float4*)(op + (size_t)(ycb + tx * 16) * W + xb) =
        make_float4(accL[tx * 4 + 0], accL[tx * 4 + 1], accL[tx * 4 + 2], accL[tx * 4 + 3]);
  }
  minmax_reduce4(lmn, lmx, mm, red, orig & (NSLOT - 1));
}

// ---------- normalize ----------

__global__ __launch_bounds__(256) void msr_norm(float* __restrict__ out,
                                                const unsigned* __restrict__ mm) {
  const size_t i = ((size_t)blockIdx.x * 256 + threadIdx.x) * 4;
  const float mn = fdec(mm[2 * NSLOT]);
  const float mx = fdec(mm[2 * NSLOT + 1]);
  const float sc = 255.f / (mx - mn);
  float4 v = *(float4*)(out + i);
  v.x = (v.x - mn) * sc;
  v.y = (v.y - mn) * sc;
  v.z = (v.z - mn) * sc;
  v.w = (v.w - mn) * sc;
  *(float4*)(out + i) = v;
}

// ---------- host-side weights (mirrors reference float math) ----------

static void compute_weights(Weights* wt) {
  memset(wt, 0, sizeof(Weights));
  const int   ntap[3]  = {161, 81, 31};
  const int   off[3]   = {0, 161, 242};
  const float sigma[3] = {80.f, 40.f, 15.f};
  for (int s = 0; s < 3; ++s) {
    const int k = ntap[s];
    float g[161];
    float sum = 0.f;
    for (int i = 0; i < k; ++i) {
      float x = (float)i - (float)(k - 1) * 0.5f;
      g[i] = expf(-(x * x) / (2.f * sigma[s] * sigma[s]));
      sum += g[i];
    }
    const float inv = 1.f / sum;
    for (int i = 0; i < k; ++i) wt->w[off[s] + i] = g[i] * inv;
  }
}

// ---------- launch ----------

extern "C" void kernel_launch(void* const* d_in, const int* in_sizes, int n_in,
                              void* d_out, int out_size, void* d_ws, size_t ws_size,
                              hipStream_t stream) {
  const float* img = (const float*)d_in[0];
  float* out = (float*)d_out;
  unsigned* mm = (unsigned*)d_ws;                   // 130 uints (64 pairs + final pair)
  ushort* frag = (ushort*)((char*)d_ws + 1024);
  ushort* planesT = (ushort*)((char*)d_ws + 32768);

  Weights wt;
  compute_weights(&wt);

  msr_fraginit<<<1, 256, 0, stream>>>(wt, frag, mm);
  msr_hblur3<<<dim3(8, 32, NP), 128, 0, stream>>>(img, planesT, (const bf16x8*)frag);
  msr_vblur3<<<dim3(16, 8, NP), 256, 0, stream>>>(planesT, img, out, (const bf16x8*)frag, mm);
  msr_mmred<<<1, 64, 0, stream>>>(mm);
  msr_norm<<<(unsigned)((size_t)NP * HW / 1024), 256, 0, stream>>>(out, mm);
}